// Round 9
// baseline (364.800 us; speedup 1.0000x reference)
//
#include <hip/hip_runtime.h>

#define N_NODES 20000
#define N_EDGES 640000
#define D 128
#define CAP 128      // bucket capacity per node
#define NBINS 157    // ceil(20000/128) coarse bins, 128 nodes each
#define LCAP 48      // per-block per-bin LDS capacity (lambda ~13)
#define BINCAP 5120  // global per-bin capacity (mean 4076, +16 sigma)

typedef __attribute__((ext_vector_type(8))) short bf16x8;
typedef __attribute__((ext_vector_type(4))) float f32x4;

__device__ __forceinline__ short f2bf(float f) {
    union { float f; unsigned u; } un; un.f = f;
    unsigned r = un.u + 0x7fff + ((un.u >> 16) & 1);
    return (short)(r >> 16);
}
__device__ __forceinline__ float bflo(unsigned u) { return __uint_as_float(u << 16); }
__device__ __forceinline__ float bfhi(unsigned u) { return __uint_as_float(u & 0xffff0000u); }

// ---------------------------------------------------------------------------
// prep1:
//   blocks [0,313):     coarse-bin edges: LDS pre-bin, bulk append to gbins
//   blocks [313,2813):  convert x -> bf16
//   blocks [2813,2845): pack W1/W2 into MFMA B-fragment layout
// ---------------------------------------------------------------------------
__global__ __launch_bounds__(256) void prep1_kernel(
    const float* __restrict__ x,
    const int* __restrict__ src, const int* __restrict__ dst,
    const float* __restrict__ W1_rel, const float* __restrict__ W1_root,
    const float* __restrict__ W2_rel, const float* __restrict__ W2_root,
    int* __restrict__ gbincnt, unsigned* __restrict__ gbins,
    short* __restrict__ xb, short* __restrict__ wpk1, short* __restrict__ wpk2)
{
    __shared__ unsigned lbin[NBINS * LCAP];
    __shared__ int lbincnt[NBINS];

    const int b = blockIdx.x;
    const int tid = threadIdx.x;

    if (b < 313) {
        // ---- zero LDS counters ----
        for (int i = tid; i < NBINS; i += 256) lbincnt[i] = 0;
        __syncthreads();

        // ---- read 8 edges/thread, LDS-bin ----
        int base4 = (b * 256 + tid) * 2;
#pragma unroll
        for (int h = 0; h < 2; h++) {
            int e4 = base4 + h;
            if (e4 < N_EDGES / 4) {
                int4 s4 = ((const int4*)src)[e4];
                int4 d4 = ((const int4*)dst)[e4];
#pragma unroll
                for (int q = 0; q < 4; q++) {
                    int d = (&d4.x)[q];
                    int s = (&s4.x)[q];
                    int bin = d >> 7;
                    int lpos = atomicAdd(&lbincnt[bin], 1);
                    if (lpos < LCAP)
                        lbin[bin * LCAP + lpos] = ((unsigned)d << 16) | (unsigned)s;
                }
            }
        }
        __syncthreads();

        // ---- bulk append: wave per bin, one global atomic per bin ----
        const int wid = tid >> 6;
        const int lane = tid & 63;
        for (int b2 = wid; b2 < NBINS; b2 += 4) {
            int lcnt = lbincnt[b2];
            lcnt = (lcnt > LCAP) ? LCAP : lcnt;
            int gbase = 0;
            if (lane == 0 && lcnt > 0) gbase = atomicAdd(&gbincnt[b2], lcnt);
            gbase = __shfl(gbase, 0, 64);
            if (lane < lcnt) {
                int gpos = gbase + lane;
                if (gpos < BINCAP)
                    gbins[b2 * BINCAP + gpos] = lbin[b2 * LCAP + lane];
            }
        }
    } else if (b < 2813) {
        int i = (b - 313) * 256 + tid;
        float4 v = ((const float4*)x)[i];
        ushort4 o;
        o.x = (unsigned short)f2bf(v.x);
        o.y = (unsigned short)f2bf(v.y);
        o.z = (unsigned short)f2bf(v.z);
        o.w = (unsigned short)f2bf(v.w);
        ((ushort4*)xb)[i] = o;
    } else {
        int pb  = b - 2813;
        int job = pb >> 4;                   // 0 -> layer1, 1 -> layer2
        int idx = (pb & 15) * 256 + tid;     // 0..4095
        const float* Wrel  = job ? W2_rel  : W1_rel;
        const float* Wroot = job ? W2_root : W1_root;
        short* Wpk = job ? wpk2 : wpk1;
        int lane = idx & 63;
        int ct   = (idx >> 6) & 7;
        int t    = idx >> 9;
        const float* W = (t < 4) ? Wrel : Wroot;
        int k0  = (t & 3) * 32 + (lane >> 4) * 8;
        int col = ct * 16 + (lane & 15);
        bf16x8 pk;
#pragma unroll
        for (int j = 0; j < 8; j++)
            pk[j] = f2bf(W[(size_t)(k0 + j) * D + col]);
        ((bf16x8*)Wpk)[idx] = pk;
    }
}

// ---------------------------------------------------------------------------
// prep2: one block per coarse bin. Scatter bin's edges into the bin's private
// 32KB bucket window via LDS cursors (L2-captured), write cnt directly.
// ---------------------------------------------------------------------------
__global__ __launch_bounds__(256) void prep2_kernel(
    const int* __restrict__ gbincnt, const unsigned* __restrict__ gbins,
    int* __restrict__ cnt, unsigned short* __restrict__ buckets)
{
    __shared__ int lcur[128];
    const int b = blockIdx.x;
    const int tid = threadIdx.x;
    if (tid < 128) lcur[tid] = 0;
    __syncthreads();

    int m = gbincnt[b];
    m = (m > BINCAP) ? BINCAP : m;
    const unsigned* bin = gbins + b * BINCAP;
    for (int i = tid; i < m; i += 256) {
        unsigned pk = bin[i];
        int d = (int)(pk >> 16);
        int s = (int)(pk & 0xffffu);
        int pos = atomicAdd(&lcur[d & 127], 1);
        if (pos < CAP) buckets[(d << 7) + pos] = (unsigned short)s;
    }
    __syncthreads();

    int node = b * 128 + tid;
    if (tid < 128 && node < N_NODES) {
        int c = lcur[tid];
        cnt[node] = (c > CAP) ? CAP : c;
    }
}

// ---------------------------------------------------------------------------
// Fused layer: out = [relu]( agg @ Wrel + b + x @ Wroot ), virtual K=256 GEMM.
// 512 threads, 16 nodes/block. Phase 1: half-wave gather per node (whole
// bucket as uint2/lane + shfl broadcast, 8 gathers in flight) -> LDS.
// Phase 2: wave = 16-col tile, MFMA over K=256 (LDS agg + global x + Wpk).
// ---------------------------------------------------------------------------
template <bool RELU, bool OUT_BF16>
__global__ __launch_bounds__(512) void layer_kernel(
    const short* __restrict__ xin,
    const int* __restrict__ cnt,
    const unsigned short* __restrict__ buckets,
    const short* __restrict__ Wpk,
    const float* __restrict__ brel,
    void* __restrict__ outp)
{
    __shared__ short sAgg[16][136];

    const int tid  = threadIdx.x;
    const int row0 = blockIdx.x * 16;

    {
        const int hw   = tid >> 5;
        const int lane = tid & 31;
        const int node = row0 + hw;
        int n = cnt[node];
        n = (n > CAP) ? CAP : n;
        uint2 idxpk = *(const uint2*)(buckets + (node << 7) + lane * 4);

        float4 acc = make_float4(0.f, 0.f, 0.f, 0.f);
        int i = 0;
        for (; i + 8 <= n; i += 8) {
            int baseLane = i >> 2;
            uint2 u[8];
#pragma unroll
            for (int q = 0; q < 8; q++) {
                unsigned word = __shfl((q & 2) ? idxpk.y : idxpk.x,
                                       baseLane + (q >> 2), 32);
                unsigned sidx = (q & 1) ? (word >> 16) : (word & 0xffffu);
                u[q] = *(const uint2*)(xin + (size_t)sidx * D + lane * 4);
            }
#pragma unroll
            for (int q = 0; q < 8; q++) {
                acc.x += bflo(u[q].x); acc.y += bfhi(u[q].x);
                acc.z += bflo(u[q].y); acc.w += bfhi(u[q].y);
            }
        }
        for (; i < n; i++) {
            unsigned word = __shfl((i & 2) ? idxpk.y : idxpk.x, i >> 2, 32);
            unsigned sidx = (i & 1) ? (word >> 16) : (word & 0xffffu);
            uint2 u0 = *(const uint2*)(xin + (size_t)sidx * D + lane * 4);
            acc.x += bflo(u0.x); acc.y += bfhi(u0.x);
            acc.z += bflo(u0.y); acc.w += bfhi(u0.y);
        }
        ushort4 o;
        o.x = (unsigned short)f2bf(acc.x);
        o.y = (unsigned short)f2bf(acc.y);
        o.z = (unsigned short)f2bf(acc.z);
        o.w = (unsigned short)f2bf(acc.w);
        *(ushort4*)&sAgg[hw][lane * 4] = o;
    }
    __syncthreads();

    const int wave = tid >> 6;
    const int lane = tid & 63;
    const int quad = lane >> 4;
    const int l16  = lane & 15;

    f32x4 acc = (f32x4){0.f, 0.f, 0.f, 0.f};
    const short* arow_x = xin + (size_t)(row0 + l16) * D + quad * 8;
    const bf16x8* wb = (const bf16x8*)Wpk + lane;

#pragma unroll
    for (int t = 0; t < 8; t++) {
        bf16x8 a;
        if (t < 4)
            a = *(const bf16x8*)&sAgg[l16][(t & 3) * 32 + quad * 8];
        else
            a = *(const bf16x8*)(arow_x + (t & 3) * 32);
        bf16x8 bfr = wb[(t * 8 + wave) * 64];
        acc = __builtin_amdgcn_mfma_f32_16x16x32_bf16(a, bfr, acc, 0, 0, 0);
    }

    const int col  = wave * 16 + l16;
    const int orow = row0 + quad * 4;
    const float bias = brel[col];
#pragma unroll
    for (int r = 0; r < 4; r++) {
        float v = acc[r] + bias;
        if (RELU) v = fmaxf(v, 0.f);
        if (OUT_BF16)
            ((short*)outp)[(size_t)(orow + r) * D + col] = f2bf(v);
        else
            ((float*)outp)[(size_t)(orow + r) * D + col] = v;
    }
}

// ---------------------------------------------------------------------------
extern "C" void kernel_launch(void* const* d_in, const int* in_sizes, int n_in,
                              void* d_out, int out_size, void* d_ws, size_t ws_size,
                              hipStream_t stream) {
    const float* x       = (const float*)d_in[0];
    const int*   ei      = (const int*)  d_in[1];
    const float* W1_rel  = (const float*)d_in[2];
    const float* b1_rel  = (const float*)d_in[3];
    const float* W1_root = (const float*)d_in[4];
    const float* W2_rel  = (const float*)d_in[5];
    const float* b2_rel  = (const float*)d_in[6];
    const float* W2_root = (const float*)d_in[7];
    float* out = (float*)d_out;

    // ws layout (16B-aligned blocks)
    char* p = (char*)d_ws;
    short* xb   = (short*)p;  p += (size_t)N_NODES * D * 2;     // 5.12 MB
    short* hb   = (short*)p;  p += (size_t)N_NODES * D * 2;     // 5.12 MB
    short* wpk1 = (short*)p;  p += 65536;                       // 64 KB
    short* wpk2 = (short*)p;  p += 65536;                       // 64 KB
    int*   cnt  = (int*)p;    p += (size_t)N_NODES * 4;         // 80 KB
    unsigned short* buckets = (unsigned short*)p;
    p += (size_t)N_NODES * CAP * 2;                             // 5.12 MB
    int* gbincnt = (int*)p;   p += 4096;                        // 157 ints, padded
    unsigned* gbins = (unsigned*)p;                             // 3.2 MB

    const int* src = ei;
    const int* dst = ei + N_EDGES;

    const int layerblocks = N_NODES / 16;   // 1250

    // ---- prep ----
    hipMemsetAsync(gbincnt, 0, 4096, stream);
    prep1_kernel<<<2845, 256, 0, stream>>>(
        x, src, dst, W1_rel, W1_root, W2_rel, W2_root,
        gbincnt, gbins, xb, wpk1, wpk2);
    prep2_kernel<<<NBINS, 256, 0, stream>>>(gbincnt, gbins, cnt, buckets);

    // ---- layer 1 (x -> hb, bf16, relu) ----
    layer_kernel<true, true><<<layerblocks, 512, 0, stream>>>(
        xb, cnt, buckets, wpk1, b1_rel, (void*)hb);

    // ---- layer 2 (hb -> out, fp32) ----
    layer_kernel<false, false><<<layerblocks, 512, 0, stream>>>(
        hb, cnt, buckets, wpk2, b2_rel, (void*)out);
}

// Round 10
// 161.038 us; speedup vs baseline: 2.2653x; 2.2653x over previous
//
#include <hip/hip_runtime.h>

#define N_NODES 20000
#define N_EDGES 640000
#define D 128
#define CAP 128      // bucket capacity per node
#define NREG 8       // dst regions (one per XCD under round-robin dispatch)
#define REGSZ 2500   // nodes per region

typedef __attribute__((ext_vector_type(8))) short bf16x8;
typedef __attribute__((ext_vector_type(4))) float f32x4;

__device__ __forceinline__ short f2bf(float f) {
    union { float f; unsigned u; } un; un.f = f;
    unsigned r = un.u + 0x7fff + ((un.u >> 16) & 1);
    return (short)(r >> 16);
}
__device__ __forceinline__ float bflo(unsigned u) { return __uint_as_float(u << 16); }
__device__ __forceinline__ float bfhi(unsigned u) { return __uint_as_float(u & 0xffff0000u); }

// ---------------------------------------------------------------------------
// Fused prep:
//   blocks [0,5000):    XCD-partitioned fill: chunk = b>>3, region = b&7;
//                       block writes only edges with dst/2500 == region, so
//                       each region's bucket slice is written by one XCD.
//   blocks [5000,7500): convert x -> bf16
//   blocks [7500,7532): pack W1/W2 into MFMA B-fragment layout
// ---------------------------------------------------------------------------
__global__ __launch_bounds__(256) void prep_kernel(
    const float* __restrict__ x,
    const int* __restrict__ src, const int* __restrict__ dst,
    const float* __restrict__ W1_rel, const float* __restrict__ W1_root,
    const float* __restrict__ W2_rel, const float* __restrict__ W2_root,
    int* __restrict__ cnt, unsigned short* __restrict__ buckets,
    short* __restrict__ xb, short* __restrict__ wpk1, short* __restrict__ wpk2)
{
    const int b = blockIdx.x;
    const int tid = threadIdx.x;
    if (b < 5000) {
        const int chunk  = b >> 3;
        const int region = b & (NREG - 1);
        int e4 = chunk * 256 + tid;          // edge quad index
        int4 s4 = ((const int4*)src)[e4];
        int4 d4 = ((const int4*)dst)[e4];
#pragma unroll
        for (int q = 0; q < 4; q++) {
            int d = (&d4.x)[q];
            int s = (&s4.x)[q];
            if (d / REGSZ == region) {
                int p = atomicAdd(&cnt[d], 1);
                if (p < CAP) buckets[(d << 7) + p] = (unsigned short)s;
            }
        }
    } else if (b < 7500) {
        int i = (b - 5000) * 256 + tid;
        float4 v = ((const float4*)x)[i];
        ushort4 o;
        o.x = (unsigned short)f2bf(v.x);
        o.y = (unsigned short)f2bf(v.y);
        o.z = (unsigned short)f2bf(v.z);
        o.w = (unsigned short)f2bf(v.w);
        ((ushort4*)xb)[i] = o;
    } else {
        int pb  = b - 7500;
        int job = pb >> 4;                   // 0 -> layer1, 1 -> layer2
        int idx = (pb & 15) * 256 + tid;     // 0..4095
        const float* Wrel  = job ? W2_rel  : W1_rel;
        const float* Wroot = job ? W2_root : W1_root;
        short* Wpk = job ? wpk2 : wpk1;
        int lane = idx & 63;
        int ct   = (idx >> 6) & 7;
        int t    = idx >> 9;
        const float* W = (t < 4) ? Wrel : Wroot;
        int k0  = (t & 3) * 32 + (lane >> 4) * 8;
        int col = ct * 16 + (lane & 15);
        bf16x8 pk;
#pragma unroll
        for (int j = 0; j < 8; j++)
            pk[j] = f2bf(W[(size_t)(k0 + j) * D + col]);
        ((bf16x8*)Wpk)[idx] = pk;
    }
}

// ---------------------------------------------------------------------------
// Fused layer: out = [relu]( agg @ Wrel + b + x @ Wroot ), virtual K=256 GEMM.
// 512 threads, 16 nodes/block. Phase 1: half-wave gather per node (whole
// bucket as uint2/lane + shfl broadcast, 8 gathers in flight) -> LDS.
// Phase 2: wave = 16-col tile, MFMA over K=256 (LDS agg + global x + Wpk).
// ---------------------------------------------------------------------------
template <bool RELU, bool OUT_BF16>
__global__ __launch_bounds__(512) void layer_kernel(
    const short* __restrict__ xin,
    const int* __restrict__ cnt,
    const unsigned short* __restrict__ buckets,
    const short* __restrict__ Wpk,
    const float* __restrict__ brel,
    void* __restrict__ outp)
{
    __shared__ short sAgg[16][136];

    const int tid  = threadIdx.x;
    const int row0 = blockIdx.x * 16;

    {
        const int hw   = tid >> 5;
        const int lane = tid & 31;
        const int node = row0 + hw;
        int n = cnt[node];
        n = (n > CAP) ? CAP : n;
        uint2 idxpk = *(const uint2*)(buckets + (node << 7) + lane * 4);

        float4 acc = make_float4(0.f, 0.f, 0.f, 0.f);
        int i = 0;
        for (; i + 8 <= n; i += 8) {
            int baseLane = i >> 2;
            uint2 u[8];
#pragma unroll
            for (int q = 0; q < 8; q++) {
                unsigned word = __shfl((q & 2) ? idxpk.y : idxpk.x,
                                       baseLane + (q >> 2), 32);
                unsigned sidx = (q & 1) ? (word >> 16) : (word & 0xffffu);
                u[q] = *(const uint2*)(xin + (size_t)sidx * D + lane * 4);
            }
#pragma unroll
            for (int q = 0; q < 8; q++) {
                acc.x += bflo(u[q].x); acc.y += bfhi(u[q].x);
                acc.z += bflo(u[q].y); acc.w += bfhi(u[q].y);
            }
        }
        for (; i < n; i++) {
            unsigned word = __shfl((i & 2) ? idxpk.y : idxpk.x, i >> 2, 32);
            unsigned sidx = (i & 1) ? (word >> 16) : (word & 0xffffu);
            uint2 u0 = *(const uint2*)(xin + (size_t)sidx * D + lane * 4);
            acc.x += bflo(u0.x); acc.y += bfhi(u0.x);
            acc.z += bflo(u0.y); acc.w += bfhi(u0.y);
        }
        ushort4 o;
        o.x = (unsigned short)f2bf(acc.x);
        o.y = (unsigned short)f2bf(acc.y);
        o.z = (unsigned short)f2bf(acc.z);
        o.w = (unsigned short)f2bf(acc.w);
        *(ushort4*)&sAgg[hw][lane * 4] = o;
    }
    __syncthreads();

    const int wave = tid >> 6;
    const int lane = tid & 63;
    const int quad = lane >> 4;
    const int l16  = lane & 15;

    f32x4 acc = (f32x4){0.f, 0.f, 0.f, 0.f};
    const short* arow_x = xin + (size_t)(row0 + l16) * D + quad * 8;
    const bf16x8* wb = (const bf16x8*)Wpk + lane;

#pragma unroll
    for (int t = 0; t < 8; t++) {
        bf16x8 a;
        if (t < 4)
            a = *(const bf16x8*)&sAgg[l16][(t & 3) * 32 + quad * 8];
        else
            a = *(const bf16x8*)(arow_x + (t & 3) * 32);
        bf16x8 bfr = wb[(t * 8 + wave) * 64];
        acc = __builtin_amdgcn_mfma_f32_16x16x32_bf16(a, bfr, acc, 0, 0, 0);
    }

    const int col  = wave * 16 + l16;
    const int orow = row0 + quad * 4;
    const float bias = brel[col];
#pragma unroll
    for (int r = 0; r < 4; r++) {
        float v = acc[r] + bias;
        if (RELU) v = fmaxf(v, 0.f);
        if (OUT_BF16)
            ((short*)outp)[(size_t)(orow + r) * D + col] = f2bf(v);
        else
            ((float*)outp)[(size_t)(orow + r) * D + col] = v;
    }
}

// ---------------------------------------------------------------------------
extern "C" void kernel_launch(void* const* d_in, const int* in_sizes, int n_in,
                              void* d_out, int out_size, void* d_ws, size_t ws_size,
                              hipStream_t stream) {
    const float* x       = (const float*)d_in[0];
    const int*   ei      = (const int*)  d_in[1];
    const float* W1_rel  = (const float*)d_in[2];
    const float* b1_rel  = (const float*)d_in[3];
    const float* W1_root = (const float*)d_in[4];
    const float* W2_rel  = (const float*)d_in[5];
    const float* b2_rel  = (const float*)d_in[6];
    const float* W2_root = (const float*)d_in[7];
    float* out = (float*)d_out;

    // ws layout (16B-aligned blocks)
    char* p = (char*)d_ws;
    short* xb   = (short*)p;  p += (size_t)N_NODES * D * 2;   // 5.12 MB
    short* hb   = (short*)p;  p += (size_t)N_NODES * D * 2;   // 5.12 MB
    short* wpk1 = (short*)p;  p += 65536;                     // 64 KB
    short* wpk2 = (short*)p;  p += 65536;                     // 64 KB
    int*   cnt  = (int*)p;    p += (size_t)N_NODES * 4;       // 80 KB
    unsigned short* buckets = (unsigned short*)p;             // 5.12 MB

    const int* src = ei;
    const int* dst = ei + N_EDGES;

    const int layerblocks = N_NODES / 16;   // 1250

    // ---- prep: zero counters, then fused partitioned-fill+convert+pack ----
    hipMemsetAsync(cnt, 0, (size_t)N_NODES * sizeof(int), stream);
    prep_kernel<<<7532, 256, 0, stream>>>(
        x, src, dst, W1_rel, W1_root, W2_rel, W2_root,
        cnt, buckets, xb, wpk1, wpk2);

    // ---- layer 1 (x -> hb, bf16, relu) ----
    layer_kernel<true, true><<<layerblocks, 512, 0, stream>>>(
        xb, cnt, buckets, wpk1, b1_rel, (void*)hb);

    // ---- layer 2 (hb -> out, fp32) ----
    layer_kernel<false, false><<<layerblocks, 512, 0, stream>>>(
        hb, cnt, buckets, wpk2, b2_rel, (void*)out);
}